// Round 5
// baseline (588.430 us; speedup 1.0000x reference)
//
#include <hip/hip_runtime.h>
#include <hip/hip_cooperative_groups.h>
#include <cstdint>
#include <cstddef>

namespace cg = cooperative_groups;

#define N_TOT   147456      // 9*128*128
#define K_PRE   6000
#define K_POST  300
#define CAP     32768       // candidate cap (expected ~9.2K)
#define MW      188         // 6016 bits per mask row -> 188 u32 words
#define ROWS_PAD 6016
#define NCHUNK  94
#define CT      512         // mask columns per tile
#define NTILE   576         // N_TOT/256
#define MTILES  288         // 24 row-blocks * 12 col-tiles

struct Params {
    const float* scores; const float* deltas; float* out;
    uint32_t* keys; uint32_t* hist; uint32_t* meta;
    uint64_t* cand; uint32_t* top; float4* P; uint64_t* yk;
    float4* OP; float4* Q; float* Bnd; uint32_t* mask;
    uint64_t* survA; uint32_t* alist; uint32_t* nact; uint32_t* valw;
};

__constant__ float c_sizes[9] = {4.f,8.f,12.f,16.f,24.f,32.f,48.f,64.f,96.f};

// Bit-exact replication of reference box math (anchor + delta, clip).
__device__ __forceinline__ void compute_box(int idx, const float* __restrict__ deltas,
                                            float& px1, float& py1, float& pw, float& ph) {
    int a   = idx >> 14;
    int rem = idx & 16383;
    int h   = rem >> 7;
    int w   = rem & 127;
    float s    = c_sizes[a];
    float half = s * 0.5f;
    const float4 d = *(const float4*)(deltas + (size_t)a * 65536 + (size_t)rem * 4);
    float b0 = (((float)h + 0.5f) - half) + d.x;
    float b1 = (((float)w + 0.5f) - half) + d.y;
    float b2 = s + d.z;
    float b3 = s + d.w;
    b0 = fmaxf(b0, 0.0f); b1 = fmaxf(b1, 0.0f);
    b2 = fmaxf(b2, 0.0f); b3 = fmaxf(b3, 0.0f);
    float x1 = b0, y1 = b1;
    float x2 = b0 + b2, y2 = b1 + b3;
    x1 = fminf(x1, 128.0f); y1 = fminf(y1, 128.0f);
    x2 = fminf(x2, 128.0f); y2 = fminf(y2, 128.0f);
    px1 = x1; py1 = y1; pw = x2 - x1; ph = y2 - y1;
}

__device__ __forceinline__ uint32_t waveReduceSum(uint32_t v) {
    #pragma unroll
    for (int o = 32; o > 0; o >>= 1) v += __shfl_xor(v, o, 64);
    return v;
}

__global__ void __launch_bounds__(256) k_all(Params p) {
    __shared__ __align__(16) uint32_t sh[4352];   // 17.4 KB, aliased per phase
    cg::grid_group grid = cg::this_grid();
    const int tid  = threadIdx.x;
    const int bid  = blockIdx.x;
    const int nb   = gridDim.x;
    const int gtid = bid * 256 + tid;

    // ---------------- phase 0: init out/hist/meta ----------------
    if (gtid < K_POST * 4) p.out[gtid] = 0.0f;
    if (gtid < 4096) p.hist[gtid] = 0u;
    if (gtid < 16) p.meta[gtid] = 0u;
    grid.sync();                                                    // S1

    // ---------------- phase 1: keys + histogram ----------------
    for (int i = tid; i < 4096; i += 256) sh[i] = 0u;
    __syncthreads();
    for (int t = bid; t < NTILE; t += nb) {
        int idx = t * 256 + tid;
        float px1, py1, pw, ph;
        compute_box(idx, p.deltas, px1, py1, pw, ph);
        bool keep = (pw >= 3.0f) && (ph >= 3.0f);
        uint32_t key = keep ? __float_as_uint(p.scores[idx]) : 0u;
        p.keys[idx] = key;
        atomicAdd(&sh[key >> 20], 1u);
    }
    __syncthreads();
    for (int i = tid; i < 4096; i += 256) {
        uint32_t v = sh[i];
        if (v) atomicAdd(&p.hist[i], v);
    }
    grid.sync();                                                    // S2

    // ---------------- phase 2: find threshold bin (block 0) ----------------
    if (bid == 0) {
        uint32_t* lh  = sh;          // [0..4095]
        uint32_t* seg = sh + 4096;   // [0..255]
        for (int i = tid; i < 4096; i += 256) lh[i] = p.hist[i];
        __syncthreads();
        uint32_t s = 0;
        for (int q = 0; q < 16; q++) s += lh[tid * 16 + q];
        seg[tid] = s;
        __syncthreads();
        if (tid == 0) {
            uint32_t cum = 0; uint32_t found = 0u;
            for (int t = 255; t >= 0 && !found; t--) {
                if (cum + seg[t] >= K_PRE) {
                    uint32_t c2 = cum;
                    for (int q = 15; q >= 0; q--) {
                        int bin = t * 16 + q;
                        c2 += lh[bin];
                        if (c2 >= K_PRE) { p.meta[0] = (uint32_t)bin; found = 1u; break; }
                    }
                }
                cum += seg[t];
            }
            if (!found) p.meta[0] = 0u;
        }
    }
    grid.sync();                                                    // S3

    // ---------------- phase 3: compact candidates ----------------
    {
        uint32_t bstar = p.meta[0];
        for (int t = bid; t < NTILE; t += nb) {
            int idx = t * 256 + tid;
            uint32_t key = p.keys[idx];
            if ((key >> 20) >= bstar) {
                uint32_t pos = atomicAdd(p.meta + 1, 1u);
                if (pos < CAP) p.cand[pos] = ((uint64_t)key << 32) | (uint32_t)(~(uint32_t)idx);
            }
        }
    }
    grid.sync();                                                    // S4

    // ---------------- phase 4: rank by score (exact top-6000 order) ----------------
    {
        uint32_t C = p.meta[1];
        if (C > CAP) C = CAP;
        int lane = tid & 63;
        uint32_t wid = (uint32_t)(bid * 4 + (tid >> 6));
        uint32_t stride = (uint32_t)nb * 4;
        uint32_t nGroups = (C + 3) >> 2;
        for (uint32_t g = wid; g < nGroups; g += stride) {
            uint32_t b = g * 4;
            uint64_t m0 = (b + 0 < C) ? p.cand[b + 0] : ~0ull;
            uint64_t m1 = (b + 1 < C) ? p.cand[b + 1] : ~0ull;
            uint64_t m2 = (b + 2 < C) ? p.cand[b + 2] : ~0ull;
            uint64_t m3 = (b + 3 < C) ? p.cand[b + 3] : ~0ull;
            uint32_t c0 = 0, c1 = 0, c2 = 0, c3 = 0;
            for (uint32_t j = lane; j < C; j += 64) {
                uint64_t k = p.cand[j];
                c0 += (k > m0) ? 1u : 0u;
                c1 += (k > m1) ? 1u : 0u;
                c2 += (k > m2) ? 1u : 0u;
                c3 += (k > m3) ? 1u : 0u;
            }
            c0 = waveReduceSum(c0); c1 = waveReduceSum(c1);
            c2 = waveReduceSum(c2); c3 = waveReduceSum(c3);
            if (lane == 0) {
                if (b + 0 < C && c0 < K_PRE) p.top[c0] = ~((uint32_t)m0);
                if (b + 1 < C && c1 < K_PRE) p.top[c1] = ~((uint32_t)m1);
                if (b + 2 < C && c2 < K_PRE) p.top[c2] = ~((uint32_t)m2);
                if (b + 3 < C && c3 < K_PRE) p.top[c3] = ~((uint32_t)m3);
            }
        }
    }
    grid.sync();                                                    // S5

    // ---------------- phase 5: props + y2 keys ----------------
    for (int r = gtid; r < K_PRE; r += nb * 256) {
        int idx = (int)p.top[r];
        float px1, py1, pw, ph;
        compute_box(idx, p.deltas, px1, py1, pw, ph);
        p.P[r] = make_float4(px1, py1, pw, ph);
        float y2 = py1 + ph;
        p.yk[r] = ((uint64_t)__float_as_uint(y2) << 32) | (uint32_t)(~(uint32_t)r);
    }
    grid.sync();                                                    // S6

    // ---------------- phase 6: stable y2-desc rank + exact div-free boundary ----
    // pred( round(d/area) >= 0.7f ) <=> d >= Bnd; M = 0.7f - 2^-25, M*area exact
    // in double; Bnd = smallest fp32 with (double)Bnd > M*area.
    {
        int lane = tid & 63;
        uint32_t wid = (uint32_t)(bid * 4 + (tid >> 6));
        uint32_t stride = (uint32_t)nb * 4;
        for (uint32_t g = wid; g < (K_PRE / 4); g += stride) {
            uint32_t b = g * 4;
            uint64_t m0 = p.yk[b + 0], m1 = p.yk[b + 1], m2 = p.yk[b + 2], m3 = p.yk[b + 3];
            uint32_t c0 = 0, c1 = 0, c2 = 0, c3 = 0;
            for (uint32_t j = lane; j < K_PRE; j += 64) {
                uint64_t k = p.yk[j];
                c0 += (k > m0) ? 1u : 0u;
                c1 += (k > m1) ? 1u : 0u;
                c2 += (k > m2) ? 1u : 0u;
                c3 += (k > m3) ? 1u : 0u;
            }
            c0 = waveReduceSum(c0); c1 = waveReduceSum(c1);
            c2 = waveReduceSum(c2); c3 = waveReduceSum(c3);
            if (lane == 0) {
                const double Mc = (double)0.7f - 0x1.0p-25;
                uint32_t rnk[4] = {c0, c1, c2, c3};
                #pragma unroll
                for (int q = 0; q < 4; q++) {
                    float4 pp = p.P[b + q];
                    uint32_t cnt = rnk[q];
                    p.OP[cnt] = pp;
                    float x1 = pp.x, y1 = pp.y;
                    float x2 = x1 + pp.z, y2 = y1 + pp.w;
                    float area = fmaxf((x2 - x1) * (y2 - y1), 1e-6f);
                    p.Q[cnt] = make_float4(x1, y1, x2, y2);
                    double c = Mc * (double)area;       // exact
                    float Bf = (float)c;
                    if (!((double)Bf > c)) Bf = __int_as_float(__float_as_int(Bf) + 1);
                    p.Bnd[cnt] = Bf;
                }
            }
        }
    }
    grid.sync();                                                    // S7

    // ---------------- phase 7: suppression bitmask (tiled, div-free) ----------
    {
        float4* qs = (float4*)sh;          // 512 * 16 B
        float*  bs = (float*)(sh + 2048);  // 512 * 4 B (byte offset 8192)
        for (int t = bid; t < MTILES; t += nb) {
            int rb = t % 24, cb = t / 24;
            int i  = rb * 256 + tid;
            int c0 = cb * CT;
            int ncols = min(CT, K_PRE - c0);
            __syncthreads();
            for (int j = tid; j < ncols; j += 256) {
                qs[j] = p.Q[c0 + j];
                bs[j] = p.Bnd[c0 + j];
            }
            __syncthreads();
            bool rowok = (i < K_PRE);
            float4 qi = rowok ? p.Q[i] : make_float4(0.f, 0.f, 0.f, 0.f);
            int nw = (ncols + 31) >> 5;
            for (int w = 0; w < nw; w++) {
                uint32_t bits = 0u;
                int jb = w * 32;
                int jn = min(32, ncols - jb);
                #pragma unroll 8
                for (int b = 0; b < jn; b++) {
                    int j = jb + b;
                    float4 qj = qs[j];
                    float iw = fminf(qi.z, qj.z) - fmaxf(qi.x, qj.x) + 1.0f;
                    iw = fmaxf(iw, 0.0f);
                    float ih = fminf(qi.w, qj.w) - fmaxf(qi.y, qj.y) + 1.0f;
                    ih = fmaxf(ih, 0.0f);
                    float d = iw * ih;
                    bits |= (d >= bs[j]) ? (1u << b) : 0u;
                }
                if (rowok) {
                    int gj = c0 + jb;
                    uint32_t selfo = (uint32_t)(i - gj);
                    if (selfo < 32u) bits &= ~(1u << selfo);
                    p.mask[(size_t)i * MW + (gj >> 5)] = bits;
                }
            }
        }
    }
    grid.sync();                                                    // S8

    // ---------------- phase 8: serial active scan (block 0) ----------------
    if (bid == 0) {
        uint32_t* rem  = sh;          // [0..187]
        uint32_t* sidx = sh + 192;    // [0..63]
        // sh[256] = ns for this chunk
        for (int i = tid; i < MW; i += 256) rem[i] = 0u;
        __syncthreads();
        uint32_t nact = 0;            // wave-0-uniform
        uint2 mr = make_uint2(0u, 0u);
        if (tid < 64) mr = *(const uint2*)(p.mask + (size_t)tid * MW);   // chunk 0
        for (int c = 0; c < NCHUNK; c++) {
            int base = c * 64;
            int rows = min(64, K_PRE - base);
            if (tid < 64) {
                uint64_t v = ~(((uint64_t)rem[2 * c + 1] << 32) | (uint64_t)rem[2 * c]);
                if (rows < 64) v &= ((1ull << rows) - 1ull);
                // leader iteration: #iters == #survivors
                uint64_t work = v, surv = 0ull;
                while (work) {
                    int k = __ffsll((unsigned long long)work) - 1;
                    surv |= 1ull << k;
                    uint64_t rowk =
                        ((uint64_t)(uint32_t)__builtin_amdgcn_readlane((int)mr.y, k) << 32)
                      |  (uint64_t)(uint32_t)__builtin_amdgcn_readlane((int)mr.x, k);
                    work &= ~rowk;
                    work &= ~(1ull << k);
                }
                uint32_t ns = (uint32_t)__popcll(surv);
                if (tid == 0) { p.survA[c] = surv; sh[256] = ns; }
                if ((surv >> tid) & 1ull) {
                    uint32_t pref = __popcll(surv & ((1ull << tid) - 1ull));
                    uint32_t gi = (uint32_t)(base + tid);
                    sidx[pref] = gi;
                    p.alist[nact + pref] = gi;
                }
                if (surv) {           // pad sidx to x16 with first survivor (OR-idempotent)
                    uint32_t nsPad = (ns + 15u) & ~15u;
                    uint32_t first = (uint32_t)base +
                                     (uint32_t)(__ffsll((unsigned long long)surv) - 1);
                    if ((uint32_t)tid >= ns && (uint32_t)tid < nsPad) sidx[tid] = first;
                }
                nact += (uint32_t)__popcll(surv);
                if (c + 1 < NCHUNK)   // prefetch next chunk rows (overlaps OR phase)
                    mr = *(const uint2*)(p.mask + (size_t)(base + 64 + tid) * MW + 2 * (c + 1));
            }
            __syncthreads();
            int w = 2 * c + 2 + (tid - 64);
            if (tid >= 64 && w < MW) {
                uint32_t nsPad = (sh[256] + 15u) & ~15u;
                uint32_t acc = rem[w];
                for (uint32_t t2 = 0; t2 < nsPad; t2 += 16) {
                    uint32_t r[16];
                    #pragma unroll
                    for (int q = 0; q < 16; q++)
                        r[q] = p.mask[(size_t)sidx[t2 + q] * MW + w];
                    uint32_t o = 0u;
                    #pragma unroll
                    for (int q = 0; q < 16; q++) o |= r[q];
                    acc |= o;
                }
                rem[w] = acc;
            }
            __syncthreads();
        }
        if (tid == 0) p.nact[0] = nact;
    }
    grid.sync();                                                    // S9

    // ---------------- phase 9: final validity (backward kills) ----------------
    if (bid < MW) {
        uint32_t* red = sh;
        uint32_t A = p.nact[0];
        uint32_t acc = 0u;
        for (uint32_t i = tid; i < A; i += 256)
            acc |= p.mask[(size_t)p.alist[i] * MW + bid];
        red[tid] = acc;
        __syncthreads();
        #pragma unroll
        for (int s = 128; s > 0; s >>= 1) {
            if (tid < s) red[tid] |= red[tid + s];
            __syncthreads();
        }
        if (tid == 0) {
            uint64_t sv = p.survA[bid >> 1];
            uint32_t aw = (uint32_t)(sv >> ((bid & 1) * 32));
            p.valw[bid] = aw & ~red[0];
        }
    }
    grid.sync();                                                    // S10

    // ---------------- phase 10: emit first 300 valid rows (block 0) -----------
    if (bid == 0) {
        uint32_t* vw   = sh;         // [0..187]
        uint32_t* pref = sh + 192;   // [0..187]
        if (tid < MW) vw[tid] = p.valw[tid];
        __syncthreads();
        if (tid == 0) {
            uint32_t run = 0;
            for (int w = 0; w < MW; w++) { pref[w] = run; run += (uint32_t)__popc(vw[w]); }
        }
        __syncthreads();
        if (tid < MW) {
            uint32_t b = vw[tid];
            if (tid == MW - 1) b &= 0xFFFFu;
            uint32_t r = pref[tid];
            int basebit = tid * 32;
            while (b && r < K_POST) {
                int bit = __ffs(b) - 1;
                b &= b - 1u;
                float4 pp = p.OP[basebit + bit];
                *(float4*)(p.out + (size_t)r * 4) = pp;
                r++;
            }
        }
    }
}

extern "C" void kernel_launch(void* const* d_in, const int* in_sizes, int n_in,
                              void* d_out, int out_size, void* d_ws, size_t ws_size,
                              hipStream_t stream) {
    (void)in_sizes; (void)n_in; (void)out_size; (void)ws_size;
    char* ws = (char*)d_ws;
    size_t off = 0;
    auto alloc = [&](size_t bytes) -> void* {
        void* pp = ws + off;
        off += (bytes + 255) & ~(size_t)255;
        return pp;
    };
    Params p;
    p.scores = (const float*)d_in[0];
    p.deltas = (const float*)d_in[1];
    p.out    = (float*)d_out;
    p.keys  = (uint32_t*)alloc((size_t)N_TOT * 4);
    p.hist  = (uint32_t*)alloc(4096 * 4);
    p.meta  = (uint32_t*)alloc(64);
    p.cand  = (uint64_t*)alloc((size_t)CAP * 8);
    p.top   = (uint32_t*)alloc((size_t)K_PRE * 4);
    p.P     = (float4*)alloc((size_t)K_PRE * 16);
    p.yk    = (uint64_t*)alloc((size_t)K_PRE * 8);
    p.OP    = (float4*)alloc((size_t)K_PRE * 16);
    p.Q     = (float4*)alloc((size_t)K_PRE * 16);
    p.Bnd   = (float*)alloc((size_t)K_PRE * 4);
    p.mask  = (uint32_t*)alloc((size_t)ROWS_PAD * MW * 4);   // ~4.5 MB
    p.survA = (uint64_t*)alloc((size_t)NCHUNK * 8);
    p.alist = (uint32_t*)alloc((size_t)K_PRE * 4);
    p.nact  = (uint32_t*)alloc(64);
    p.valw  = (uint32_t*)alloc((size_t)MW * 4);

    void* args[] = { (void*)&p };
    hipLaunchCooperativeKernel((void*)k_all, dim3(256), dim3(256), args, 0, stream);
}

// Round 7
// 285.337 us; speedup vs baseline: 2.0622x; 2.0622x over previous
//
#include <hip/hip_runtime.h>
#include <cstdint>
#include <cstddef>

#define N_TOT   147456      // 9*128*128
#define K_PRE   6000
#define K_POST  300
#define CAP     32768       // candidate cap (expected ~9.2K)
#define MW      188         // 6016 bits per mask row -> 188 u32 words
#define ROWS_PAD 6016
#define NCHUNK  94
#define CT      512         // k_mask columns per tile
#define ROWB    24
#define COLB    12

__constant__ float c_sizes[9] = {4.f,8.f,12.f,16.f,24.f,32.f,48.f,64.f,96.f};

// Bit-exact replication of reference box math (anchor + delta, clip).
__device__ __forceinline__ void compute_box(int idx, const float* __restrict__ deltas,
                                            float& px1, float& py1, float& pw, float& ph) {
    int a   = idx >> 14;
    int rem = idx & 16383;
    int h   = rem >> 7;
    int w   = rem & 127;
    float s    = c_sizes[a];
    float half = s * 0.5f;
    const float4 d = *(const float4*)(deltas + (size_t)a * 65536 + (size_t)rem * 4);
    float b0 = (((float)h + 0.5f) - half) + d.x;
    float b1 = (((float)w + 0.5f) - half) + d.y;
    float b2 = s + d.z;
    float b3 = s + d.w;
    b0 = fmaxf(b0, 0.0f); b1 = fmaxf(b1, 0.0f);
    b2 = fmaxf(b2, 0.0f); b3 = fmaxf(b3, 0.0f);
    float x1 = b0, y1 = b1;
    float x2 = b0 + b2, y2 = b1 + b3;
    x1 = fminf(x1, 128.0f); y1 = fminf(y1, 128.0f);
    x2 = fminf(x2, 128.0f); y2 = fminf(y2, 128.0f);
    px1 = x1; py1 = y1; pw = x2 - x1; ph = y2 - y1;
}

__device__ __forceinline__ uint32_t waveReduceSum(uint32_t v) {
    #pragma unroll
    for (int o = 32; o > 0; o >>= 1) v += __shfl_xor(v, o, 64);
    return v;
}

__global__ void k_keys_hist(const float* __restrict__ scores, const float* __restrict__ deltas,
                            uint32_t* __restrict__ keys, uint32_t* __restrict__ hist) {
    __shared__ uint32_t lh[4096];
    for (int i = threadIdx.x; i < 4096; i += 256) lh[i] = 0u;
    __syncthreads();
    int idx = blockIdx.x * 256 + threadIdx.x;
    float px1, py1, pw, ph;
    compute_box(idx, deltas, px1, py1, pw, ph);
    bool keep = (pw >= 3.0f) && (ph >= 3.0f);
    float sc = scores[idx];
    uint32_t key = keep ? __float_as_uint(sc) : 0u;
    keys[idx] = key;
    atomicAdd(&lh[key >> 20], 1u);
    __syncthreads();
    for (int i = threadIdx.x; i < 4096; i += 256) {
        uint32_t v = lh[i];
        if (v) atomicAdd(&hist[i], v);
    }
}

__global__ void k_findbin(const uint32_t* __restrict__ hist, uint32_t* meta) {
    __shared__ uint32_t lh[4096];
    __shared__ uint32_t seg[256];
    for (int i = threadIdx.x; i < 4096; i += 256) lh[i] = hist[i];
    __syncthreads();
    uint32_t s = 0;
    for (int q = 0; q < 16; q++) s += lh[threadIdx.x * 16 + q];
    seg[threadIdx.x] = s;
    __syncthreads();
    if (threadIdx.x == 0) {
        uint32_t cum = 0;
        for (int t = 255; t >= 0; t--) {
            if (cum + seg[t] >= K_PRE) {
                uint32_t c2 = cum;
                for (int q = 15; q >= 0; q--) {
                    int bin = t * 16 + q;
                    c2 += lh[bin];
                    if (c2 >= K_PRE) { meta[0] = (uint32_t)bin; return; }
                }
            }
            cum += seg[t];
        }
        meta[0] = 0u;
    }
}

__global__ void k_compact(const uint32_t* __restrict__ keys, const uint32_t* __restrict__ meta,
                          uint64_t* __restrict__ cand, uint32_t* counter) {
    int idx = blockIdx.x * 256 + threadIdx.x;
    uint32_t bstar = meta[0];
    uint32_t key = keys[idx];
    if ((key >> 20) >= bstar) {
        uint32_t pos = atomicAdd(counter, 1u);
        if (pos < CAP) cand[pos] = ((uint64_t)key << 32) | (uint32_t)(~(uint32_t)idx);
    }
}

// rank-by-count (exact top_k order: score desc, idx asc) fused with props/ykey
// generation: rank r in [0,6000) gets P[r] (box) and yk[r] (y2-desc stable key).
__global__ void k_rank_props(const uint64_t* __restrict__ cand, const uint32_t* __restrict__ meta,
                             const float* __restrict__ deltas,
                             float4* __restrict__ P, uint64_t* __restrict__ yk) {
    uint32_t C = meta[1];
    if (C > CAP) C = CAP;
    int lane = threadIdx.x & 63;
    uint32_t wid = (uint32_t)(blockIdx.x * 4 + (threadIdx.x >> 6));
    uint32_t stride = gridDim.x * 4;
    uint32_t nGroups = (C + 3) >> 2;
    for (uint32_t g = wid; g < nGroups; g += stride) {
        uint32_t b = g * 4;
        uint64_t m0 = (b + 0 < C) ? cand[b + 0] : ~0ull;
        uint64_t m1 = (b + 1 < C) ? cand[b + 1] : ~0ull;
        uint64_t m2 = (b + 2 < C) ? cand[b + 2] : ~0ull;
        uint64_t m3 = (b + 3 < C) ? cand[b + 3] : ~0ull;
        uint32_t c0 = 0, c1 = 0, c2 = 0, c3 = 0;
        for (uint32_t j = lane; j < C; j += 64) {
            uint64_t k = cand[j];
            c0 += (k > m0) ? 1u : 0u;
            c1 += (k > m1) ? 1u : 0u;
            c2 += (k > m2) ? 1u : 0u;
            c3 += (k > m3) ? 1u : 0u;
        }
        c0 = waveReduceSum(c0); c1 = waveReduceSum(c1);
        c2 = waveReduceSum(c2); c3 = waveReduceSum(c3);
        if (lane == 0) {
            uint64_t mm[4] = {m0, m1, m2, m3};
            uint32_t cc[4] = {c0, c1, c2, c3};
            #pragma unroll
            for (int q = 0; q < 4; q++) {
                if (b + q < C && cc[q] < K_PRE) {
                    uint32_t r = cc[q];
                    int idx = (int)(~((uint32_t)mm[q]));
                    float px1, py1, pw, ph;
                    compute_box(idx, deltas, px1, py1, pw, ph);
                    P[r] = make_float4(px1, py1, pw, ph);
                    float y2 = py1 + ph;
                    yk[r] = ((uint64_t)__float_as_uint(y2) << 32) | (uint32_t)(~r);
                }
            }
        }
    }
}

// stable y2-desc rank; writes y2-ordered props OP, corners Q, and the exact
// div-free boundary: pred( round(d/area) >= 0.7f ) <=> d >= Bnd.
// M = 0.7f - 2^-25; M*(double)area exact; Bnd = smallest fp32 > M*area.
__global__ void k_rank_y2(const uint64_t* __restrict__ ykey, const float4* __restrict__ P,
                          float4* __restrict__ OP, float4* __restrict__ Q, float* __restrict__ Bnd) {
    int lane = threadIdx.x & 63;
    int wid  = (blockIdx.x * 256 + threadIdx.x) >> 6;   // 0..1499
    uint32_t b = wid * 4;
    uint64_t m0 = ykey[b + 0], m1 = ykey[b + 1], m2 = ykey[b + 2], m3 = ykey[b + 3];
    uint32_t c0 = 0, c1 = 0, c2 = 0, c3 = 0;
    for (uint32_t j = lane; j < K_PRE; j += 64) {
        uint64_t k = ykey[j];
        c0 += (k > m0) ? 1u : 0u;
        c1 += (k > m1) ? 1u : 0u;
        c2 += (k > m2) ? 1u : 0u;
        c3 += (k > m3) ? 1u : 0u;
    }
    c0 = waveReduceSum(c0); c1 = waveReduceSum(c1);
    c2 = waveReduceSum(c2); c3 = waveReduceSum(c3);
    if (lane == 0) {
        const double Mc = (double)0.7f - 0x1.0p-25;
        uint32_t rnk[4] = {c0, c1, c2, c3};
        #pragma unroll
        for (int q = 0; q < 4; q++) {
            float4 p = P[b + q];
            uint32_t cnt = rnk[q];
            OP[cnt] = p;
            float x1 = p.x, y1 = p.y;
            float x2 = x1 + p.z, y2 = y1 + p.w;
            float area = fmaxf((x2 - x1) * (y2 - y1), 1e-6f);
            Q[cnt] = make_float4(x1, y1, x2, y2);
            double c = Mc * (double)area;       // exact
            float Bf = (float)c;
            if (!((double)Bf > c)) Bf = __int_as_float(__float_as_int(Bf) + 1);
            Bnd[cnt] = Bf;
        }
    }
}

// suppression bitmask, tiled: lanes = rows, columns LDS-broadcast; div-free.
__global__ void __launch_bounds__(256) k_mask(const float4* __restrict__ Q,
                                              const float* __restrict__ Bnd,
                                              uint32_t* __restrict__ mask) {
    __shared__ float4 qs[CT];
    __shared__ float  bs[CT];
    int i  = blockIdx.x * 256 + threadIdx.x;     // row
    int c0 = blockIdx.y * CT;                    // first column of tile
    int ncols = min(CT, K_PRE - c0);
    for (int j = threadIdx.x; j < ncols; j += 256) {
        qs[j] = Q[c0 + j];
        bs[j] = Bnd[c0 + j];
    }
    __syncthreads();
    bool rowok = (i < K_PRE);
    float4 qi = rowok ? Q[i] : make_float4(0.f, 0.f, 0.f, 0.f);
    int nw = (ncols + 31) >> 5;
    for (int w = 0; w < nw; w++) {
        uint32_t bits = 0u;
        int jb = w * 32;
        int jn = min(32, ncols - jb);
        #pragma unroll 8
        for (int b = 0; b < jn; b++) {
            int j = jb + b;
            float4 qj = qs[j];
            float iw = fminf(qi.z, qj.z) - fmaxf(qi.x, qj.x) + 1.0f;
            iw = fmaxf(iw, 0.0f);
            float ih = fminf(qi.w, qj.w) - fmaxf(qi.y, qj.y) + 1.0f;
            ih = fmaxf(ih, 0.0f);
            float d = iw * ih;
            bits |= (d >= bs[j]) ? (1u << b) : 0u;
        }
        if (rowok) {
            int gj = c0 + jb;
            uint32_t selfo = (uint32_t)(i - gj);
            if (selfo < 32u) bits &= ~(1u << selfo);     // j == i excluded
            mask[(size_t)i * MW + (gj >> 5)] = bits;
        }
    }
}

// Serial active scan + final validity + emit, single block.
// Decide: active(i) = no earlier active k with mask[k][i]; leader iteration
// over uniform work mask, #iters == #survivors. OR phase: active rows of this
// chunk ORed into ALL 188 rem words -> at end rem = union over active rows of
// their mask rows; final valid = activeBits & ~rem (covers backward kills).
__global__ void __launch_bounds__(256) k_scan(const uint32_t* __restrict__ mask,
                                              const float4* __restrict__ OP,
                                              float* __restrict__ out) {
    __shared__ uint32_t rem[MW];
    __shared__ uint32_t sidx[64];
    __shared__ uint32_t svL[MW];
    __shared__ uint32_t nsSh;
    __shared__ uint32_t pref[MW];
    int tid = threadIdx.x;
    for (int i = tid; i < MW; i += 256) rem[i] = 0u;
    for (int i = tid; i < K_POST * 4; i += 256) out[i] = 0.0f;
    __syncthreads();
    uint2 mr = make_uint2(0u, 0u);
    if (tid < 64) mr = *(const uint2*)(mask + (size_t)tid * MW);   // chunk 0 rows
    for (int c = 0; c < NCHUNK; c++) {
        int base = c * 64;
        int rows = min(64, K_PRE - base);
        if (tid < 64) {
            uint64_t v = ~(((uint64_t)rem[2 * c + 1] << 32) | (uint64_t)rem[2 * c]);
            if (rows < 64) v &= ((1ull << rows) - 1ull);
            uint64_t work = v, surv = 0ull;
            while (work) {                      // leader iteration
                int k = __ffsll((unsigned long long)work) - 1;
                surv |= 1ull << k;
                uint64_t rowk =
                    ((uint64_t)(uint32_t)__builtin_amdgcn_readlane((int)mr.y, k) << 32)
                  |  (uint64_t)(uint32_t)__builtin_amdgcn_readlane((int)mr.x, k);
                work &= ~rowk;
                work &= ~(1ull << k);
            }
            uint32_t ns = (uint32_t)__popcll(surv);
            if (tid == 0) {
                svL[2 * c]     = (uint32_t)surv;
                svL[2 * c + 1] = (uint32_t)(surv >> 32);
                nsSh = ns;
            }
            if ((surv >> tid) & 1ull) {
                uint32_t pr = __popcll(surv & ((1ull << tid) - 1ull));
                sidx[pr] = (uint32_t)(base + tid);
            }
            if (surv) {             // pad sidx to x16 with first survivor (OR-idempotent)
                uint32_t nsPad = (ns + 15u) & ~15u;
                uint32_t first = (uint32_t)base +
                                 (uint32_t)(__ffsll((unsigned long long)surv) - 1);
                if ((uint32_t)tid >= ns && (uint32_t)tid < nsPad) sidx[tid] = first;
            }
            if (c + 1 < NCHUNK)     // prefetch next chunk rows (overlaps OR phase)
                mr = *(const uint2*)(mask + (size_t)(base + 64 + tid) * MW + 2 * (c + 1));
        }
        __syncthreads();
        int w = tid - 64;
        if (w >= 0 && w < MW) {
            uint32_t nsPad = (nsSh + 15u) & ~15u;
            uint32_t acc = rem[w];
            for (uint32_t t2 = 0; t2 < nsPad; t2 += 16) {
                uint32_t r[16];
                #pragma unroll
                for (int q = 0; q < 16; q++)
                    r[q] = mask[(size_t)sidx[t2 + q] * MW + w];
                uint32_t o = 0u;
                #pragma unroll
                for (int q = 0; q < 16; q++) o |= r[q];
                acc |= o;
            }
            rem[w] = acc;
        }
        __syncthreads();
    }
    // final validity + emit first 300 (tail already zeroed above)
    if (tid < MW) {
        uint32_t vv = svL[tid] & ~rem[tid];
        if (tid == MW - 1) vv &= 0xFFFFu;
        rem[tid] = vv;
    }
    __syncthreads();
    if (tid == 0) {
        uint32_t run = 0;
        for (int w2 = 0; w2 < MW; w2++) { pref[w2] = run; run += (uint32_t)__popc(rem[w2]); }
    }
    __syncthreads();
    if (tid < MW) {
        uint32_t b = rem[tid];
        uint32_t r = pref[tid];
        int basebit = tid * 32;
        while (b && r < K_POST) {
            int bit = __ffs(b) - 1;
            b &= b - 1u;
            float4 pp = OP[basebit + bit];
            *(float4*)(out + (size_t)r * 4) = pp;
            r++;
        }
    }
}

extern "C" void kernel_launch(void* const* d_in, const int* in_sizes, int n_in,
                              void* d_out, int out_size, void* d_ws, size_t ws_size,
                              hipStream_t stream) {
    (void)in_sizes; (void)n_in; (void)out_size; (void)ws_size;
    const float* scores = (const float*)d_in[0];
    const float* deltas = (const float*)d_in[1];
    float* out = (float*)d_out;

    char* ws = (char*)d_ws;
    size_t off = 0;
    auto alloc = [&](size_t bytes) -> void* {
        void* p = ws + off;
        off += (bytes + 255) & ~(size_t)255;
        return p;
    };
    uint32_t* hist  = (uint32_t*)alloc(4096 * 4);   // hist+meta contiguous: one memset
    uint32_t* meta  = (uint32_t*)alloc(64);
    uint32_t* keys  = (uint32_t*)alloc((size_t)N_TOT * 4);
    uint64_t* cand  = (uint64_t*)alloc((size_t)CAP * 8);
    float4*   P     = (float4*)alloc((size_t)K_PRE * 16);
    uint64_t* yk    = (uint64_t*)alloc((size_t)K_PRE * 8);
    float4*   OP    = (float4*)alloc((size_t)K_PRE * 16);
    float4*   Q     = (float4*)alloc((size_t)K_PRE * 16);
    float*    Bnd   = (float*)alloc((size_t)K_PRE * 4);
    uint32_t* mask  = (uint32_t*)alloc((size_t)ROWS_PAD * MW * 4);   // ~4.5 MB

    hipMemsetAsync(hist, 0, 4096 * 4 + 256, stream);   // hist + meta
    k_keys_hist<<<N_TOT / 256, 256, 0, stream>>>(scores, deltas, keys, hist);
    k_findbin<<<1, 256, 0, stream>>>(hist, meta);
    k_compact<<<N_TOT / 256, 256, 0, stream>>>(keys, meta, cand, meta + 1);
    k_rank_props<<<1024, 256, 0, stream>>>(cand, meta, deltas, P, yk);
    k_rank_y2<<<375, 256, 0, stream>>>(yk, P, OP, Q, Bnd);
    k_mask<<<dim3(ROWB, COLB), 256, 0, stream>>>(Q, Bnd, mask);
    k_scan<<<1, 256, 0, stream>>>(mask, OP, out);
}

// Round 8
// 257.247 us; speedup vs baseline: 2.2874x; 1.1092x over previous
//
#include <hip/hip_runtime.h>
#include <cstdint>
#include <cstddef>

#define N_TOT   147456      // 9*128*128
#define K_PRE   6000
#define K_POST  300
#define CAP     32768       // candidate cap (expected ~9.2K)
#define MW      188         // 6016 bits per mask row -> 188 u32 words
#define ROWS_PAD 6016
#define NCHUNK  94
#define CT      128         // k_mask columns per tile
#define ROWB    24
#define COLB    47          // ceil(6000/128)

__constant__ float c_sizes[9] = {4.f,8.f,12.f,16.f,24.f,32.f,48.f,64.f,96.f};

// Bit-exact replication of reference box math (anchor + delta, clip).
__device__ __forceinline__ void compute_box(int idx, const float* __restrict__ deltas,
                                            float& px1, float& py1, float& pw, float& ph) {
    int a   = idx >> 14;
    int rem = idx & 16383;
    int h   = rem >> 7;
    int w   = rem & 127;
    float s    = c_sizes[a];
    float half = s * 0.5f;
    const float4 d = *(const float4*)(deltas + (size_t)a * 65536 + (size_t)rem * 4);
    float b0 = (((float)h + 0.5f) - half) + d.x;
    float b1 = (((float)w + 0.5f) - half) + d.y;
    float b2 = s + d.z;
    float b3 = s + d.w;
    b0 = fmaxf(b0, 0.0f); b1 = fmaxf(b1, 0.0f);
    b2 = fmaxf(b2, 0.0f); b3 = fmaxf(b3, 0.0f);
    float x1 = b0, y1 = b1;
    float x2 = b0 + b2, y2 = b1 + b3;
    x1 = fminf(x1, 128.0f); y1 = fminf(y1, 128.0f);
    x2 = fminf(x2, 128.0f); y2 = fminf(y2, 128.0f);
    px1 = x1; py1 = y1; pw = x2 - x1; ph = y2 - y1;
}

__device__ __forceinline__ uint32_t waveReduceSum(uint32_t v) {
    #pragma unroll
    for (int o = 32; o > 0; o >>= 1) v += __shfl_xor(v, o, 64);
    return v;
}

__global__ void k_keys_hist(const float* __restrict__ scores, const float* __restrict__ deltas,
                            uint32_t* __restrict__ keys, uint32_t* __restrict__ hist) {
    __shared__ uint32_t lh[4096];
    for (int i = threadIdx.x; i < 4096; i += 256) lh[i] = 0u;
    __syncthreads();
    int idx = blockIdx.x * 256 + threadIdx.x;
    float px1, py1, pw, ph;
    compute_box(idx, deltas, px1, py1, pw, ph);
    bool keep = (pw >= 3.0f) && (ph >= 3.0f);
    float sc = scores[idx];
    uint32_t key = keep ? __float_as_uint(sc) : 0u;
    keys[idx] = key;
    atomicAdd(&lh[key >> 20], 1u);
    __syncthreads();
    for (int i = threadIdx.x; i < 4096; i += 256) {
        uint32_t v = lh[i];
        if (v) atomicAdd(&hist[i], v);
    }
}

// per-block redundant findbin (hist is L2-resident) + compact this block's slice
__global__ void k_findbin_compact(const uint32_t* __restrict__ hist,
                                  const uint32_t* __restrict__ keys,
                                  uint64_t* __restrict__ cand, uint32_t* counter) {
    __shared__ uint32_t lh[4096];
    __shared__ uint32_t seg[256];
    __shared__ uint32_t bsh;
    for (int i = threadIdx.x; i < 4096; i += 256) lh[i] = hist[i];
    __syncthreads();
    uint32_t s = 0;
    for (int q = 0; q < 16; q++) s += lh[threadIdx.x * 16 + q];
    seg[threadIdx.x] = s;
    __syncthreads();
    if (threadIdx.x == 0) {
        uint32_t cum = 0; uint32_t bstar = 0u; int found = 0;
        for (int t = 255; t >= 0 && !found; t--) {
            if (cum + seg[t] >= K_PRE) {
                uint32_t c2 = cum;
                for (int q = 15; q >= 0; q--) {
                    int bin = t * 16 + q;
                    c2 += lh[bin];
                    if (c2 >= K_PRE) { bstar = (uint32_t)bin; found = 1; break; }
                }
            }
            cum += seg[t];
        }
        bsh = bstar;
    }
    __syncthreads();
    uint32_t bstar = bsh;
    int idx = blockIdx.x * 256 + threadIdx.x;
    uint32_t key = keys[idx];
    if ((key >> 20) >= bstar) {
        uint32_t pos = atomicAdd(counter, 1u);
        if (pos < CAP) cand[pos] = ((uint64_t)key << 32) | (uint32_t)(~(uint32_t)idx);
    }
}

// rank-by-count (exact top_k order: score desc, idx asc) fused with props/ykey
// generation: rank r in [0,6000) gets P[r] (box) and yk[r] (y2-desc stable key).
__global__ void k_rank_props(const uint64_t* __restrict__ cand, const uint32_t* __restrict__ meta,
                             const float* __restrict__ deltas,
                             float4* __restrict__ P, uint64_t* __restrict__ yk) {
    uint32_t C = meta[1];
    if (C > CAP) C = CAP;
    int lane = threadIdx.x & 63;
    uint32_t wid = (uint32_t)(blockIdx.x * 4 + (threadIdx.x >> 6));
    uint32_t stride = gridDim.x * 4;
    uint32_t nGroups = (C + 3) >> 2;
    for (uint32_t g = wid; g < nGroups; g += stride) {
        uint32_t b = g * 4;
        uint64_t m0 = (b + 0 < C) ? cand[b + 0] : ~0ull;
        uint64_t m1 = (b + 1 < C) ? cand[b + 1] : ~0ull;
        uint64_t m2 = (b + 2 < C) ? cand[b + 2] : ~0ull;
        uint64_t m3 = (b + 3 < C) ? cand[b + 3] : ~0ull;
        uint32_t c0 = 0, c1 = 0, c2 = 0, c3 = 0;
        for (uint32_t j = lane; j < C; j += 64) {
            uint64_t k = cand[j];
            c0 += (k > m0) ? 1u : 0u;
            c1 += (k > m1) ? 1u : 0u;
            c2 += (k > m2) ? 1u : 0u;
            c3 += (k > m3) ? 1u : 0u;
        }
        c0 = waveReduceSum(c0); c1 = waveReduceSum(c1);
        c2 = waveReduceSum(c2); c3 = waveReduceSum(c3);
        if (lane == 0) {
            uint64_t mm[4] = {m0, m1, m2, m3};
            uint32_t cc[4] = {c0, c1, c2, c3};
            #pragma unroll
            for (int q = 0; q < 4; q++) {
                if (b + q < C && cc[q] < K_PRE) {
                    uint32_t r = cc[q];
                    int idx = (int)(~((uint32_t)mm[q]));
                    float px1, py1, pw, ph;
                    compute_box(idx, deltas, px1, py1, pw, ph);
                    P[r] = make_float4(px1, py1, pw, ph);
                    float y2 = py1 + ph;
                    yk[r] = ((uint64_t)__float_as_uint(y2) << 32) | (uint32_t)(~r);
                }
            }
        }
    }
}

// stable y2-desc rank; writes y2-ordered props OP, corners Q, and the exact
// div-free boundary: pred( round(d/area) >= 0.7f ) <=> d >= Bnd.
// M = 0.7f - 2^-25; M*(double)area exact; Bnd = smallest fp32 > M*area.
__global__ void k_rank_y2(const uint64_t* __restrict__ ykey, const float4* __restrict__ P,
                          float4* __restrict__ OP, float4* __restrict__ Q, float* __restrict__ Bnd) {
    int lane = threadIdx.x & 63;
    int wid  = (blockIdx.x * 256 + threadIdx.x) >> 6;   // 0..1499
    uint32_t b = wid * 4;
    uint64_t m0 = ykey[b + 0], m1 = ykey[b + 1], m2 = ykey[b + 2], m3 = ykey[b + 3];
    uint32_t c0 = 0, c1 = 0, c2 = 0, c3 = 0;
    for (uint32_t j = lane; j < K_PRE; j += 64) {
        uint64_t k = ykey[j];
        c0 += (k > m0) ? 1u : 0u;
        c1 += (k > m1) ? 1u : 0u;
        c2 += (k > m2) ? 1u : 0u;
        c3 += (k > m3) ? 1u : 0u;
    }
    c0 = waveReduceSum(c0); c1 = waveReduceSum(c1);
    c2 = waveReduceSum(c2); c3 = waveReduceSum(c3);
    if (lane == 0) {
        const double Mc = (double)0.7f - 0x1.0p-25;
        uint32_t rnk[4] = {c0, c1, c2, c3};
        #pragma unroll
        for (int q = 0; q < 4; q++) {
            float4 p = P[b + q];
            uint32_t cnt = rnk[q];
            OP[cnt] = p;
            float x1 = p.x, y1 = p.y;
            float x2 = x1 + p.z, y2 = y1 + p.w;
            float area = fmaxf((x2 - x1) * (y2 - y1), 1e-6f);
            Q[cnt] = make_float4(x1, y1, x2, y2);
            double c = Mc * (double)area;       // exact
            float Bf = (float)c;
            if (!((double)Bf > c)) Bf = __int_as_float(__float_as_int(Bf) + 1);
            Bnd[cnt] = Bf;
        }
    }
}

// suppression bitmask, tiled: lanes = rows, columns LDS-broadcast; div-free.
// CT=128 -> 1128 blocks (~4.4/CU) for latency hiding.
__global__ void __launch_bounds__(256) k_mask(const float4* __restrict__ Q,
                                              const float* __restrict__ Bnd,
                                              uint32_t* __restrict__ mask) {
    __shared__ float4 qs[CT];
    __shared__ float  bs[CT];
    int i  = blockIdx.x * 256 + threadIdx.x;     // row
    int c0 = blockIdx.y * CT;                    // first column of tile
    int ncols = min(CT, K_PRE - c0);
    bool rowok = (i < K_PRE);
    float4 qi = rowok ? Q[i] : make_float4(0.f, 0.f, 0.f, 0.f);
    for (int j = threadIdx.x; j < ncols; j += 256) {
        qs[j] = Q[c0 + j];
        bs[j] = Bnd[c0 + j];
    }
    __syncthreads();
    int nw = (ncols + 31) >> 5;
    for (int w = 0; w < nw; w++) {
        uint32_t bits = 0u;
        int jb = w * 32;
        int jn = min(32, ncols - jb);
        #pragma unroll 8
        for (int b = 0; b < jn; b++) {
            int j = jb + b;
            float4 qj = qs[j];
            float iw = fminf(qi.z, qj.z) - fmaxf(qi.x, qj.x) + 1.0f;
            iw = fmaxf(iw, 0.0f);
            float ih = fminf(qi.w, qj.w) - fmaxf(qi.y, qj.y) + 1.0f;
            ih = fmaxf(ih, 0.0f);
            float d = iw * ih;
            bits |= (d >= bs[j]) ? (1u << b) : 0u;
        }
        if (rowok) {
            int gj = c0 + jb;
            uint32_t selfo = (uint32_t)(i - gj);
            if (selfo < 32u) bits &= ~(1u << selfo);     // j == i excluded
            mask[(size_t)i * MW + (gj >> 5)] = bits;
        }
    }
}

// Serial active scan + final validity + emit, single block.
// Decide: active(i) = no earlier active k with mask[k][i]; leader iteration
// over uniform work mask, #iters == #survivors. OR phase: active rows of this
// chunk ORed into ALL 188 rem words -> at end rem = union over active rows of
// their mask rows; final valid = activeBits & ~rem (covers backward kills).
__global__ void __launch_bounds__(256) k_scan(const uint32_t* __restrict__ mask,
                                              const float4* __restrict__ OP,
                                              float* __restrict__ out) {
    __shared__ uint32_t rem[MW];
    __shared__ uint32_t sidx[64];
    __shared__ uint32_t svL[MW];
    __shared__ uint32_t nsSh;
    __shared__ uint32_t pref[MW];
    int tid = threadIdx.x;
    for (int i = tid; i < MW; i += 256) rem[i] = 0u;
    for (int i = tid; i < K_POST * 4; i += 256) out[i] = 0.0f;
    __syncthreads();
    uint2 mr = make_uint2(0u, 0u);
    if (tid < 64) mr = *(const uint2*)(mask + (size_t)tid * MW);   // chunk 0 rows
    for (int c = 0; c < NCHUNK; c++) {
        int base = c * 64;
        int rows = min(64, K_PRE - base);
        if (tid < 64) {
            uint64_t v = ~(((uint64_t)rem[2 * c + 1] << 32) | (uint64_t)rem[2 * c]);
            if (rows < 64) v &= ((1ull << rows) - 1ull);
            uint64_t work = v, surv = 0ull;
            while (work) {                      // leader iteration
                int k = __ffsll((unsigned long long)work) - 1;
                surv |= 1ull << k;
                uint64_t rowk =
                    ((uint64_t)(uint32_t)__builtin_amdgcn_readlane((int)mr.y, k) << 32)
                  |  (uint64_t)(uint32_t)__builtin_amdgcn_readlane((int)mr.x, k);
                work &= ~rowk;
                work &= ~(1ull << k);
            }
            uint32_t ns = (uint32_t)__popcll(surv);
            if (tid == 0) {
                svL[2 * c]     = (uint32_t)surv;
                svL[2 * c + 1] = (uint32_t)(surv >> 32);
                nsSh = ns;
            }
            if ((surv >> tid) & 1ull) {
                uint32_t pr = __popcll(surv & ((1ull << tid) - 1ull));
                sidx[pr] = (uint32_t)(base + tid);
            }
            if (surv) {             // pad sidx to x16 with first survivor (OR-idempotent)
                uint32_t nsPad = (ns + 15u) & ~15u;
                uint32_t first = (uint32_t)base +
                                 (uint32_t)(__ffsll((unsigned long long)surv) - 1);
                if ((uint32_t)tid >= ns && (uint32_t)tid < nsPad) sidx[tid] = first;
            }
            if (c + 1 < NCHUNK)     // prefetch next chunk rows (overlaps OR phase)
                mr = *(const uint2*)(mask + (size_t)(base + 64 + tid) * MW + 2 * (c + 1));
        }
        __syncthreads();
        int w = tid - 64;
        if (w >= 0 && w < MW) {
            uint32_t nsPad = (nsSh + 15u) & ~15u;
            uint32_t acc = rem[w];
            for (uint32_t t2 = 0; t2 < nsPad; t2 += 16) {
                uint32_t r[16];
                #pragma unroll
                for (int q = 0; q < 16; q++)
                    r[q] = mask[(size_t)sidx[t2 + q] * MW + w];
                uint32_t o = 0u;
                #pragma unroll
                for (int q = 0; q < 16; q++) o |= r[q];
                acc |= o;
            }
            rem[w] = acc;
        }
        __syncthreads();
    }
    // final validity + emit first 300 (tail already zeroed above)
    if (tid < MW) {
        uint32_t vv = svL[tid] & ~rem[tid];
        if (tid == MW - 1) vv &= 0xFFFFu;
        rem[tid] = vv;
    }
    __syncthreads();
    if (tid == 0) {
        uint32_t run = 0;
        for (int w2 = 0; w2 < MW; w2++) { pref[w2] = run; run += (uint32_t)__popc(rem[w2]); }
    }
    __syncthreads();
    if (tid < MW) {
        uint32_t b = rem[tid];
        uint32_t r = pref[tid];
        int basebit = tid * 32;
        while (b && r < K_POST) {
            int bit = __ffs(b) - 1;
            b &= b - 1u;
            float4 pp = OP[basebit + bit];
            *(float4*)(out + (size_t)r * 4) = pp;
            r++;
        }
    }
}

extern "C" void kernel_launch(void* const* d_in, const int* in_sizes, int n_in,
                              void* d_out, int out_size, void* d_ws, size_t ws_size,
                              hipStream_t stream) {
    (void)in_sizes; (void)n_in; (void)out_size; (void)ws_size;
    const float* scores = (const float*)d_in[0];
    const float* deltas = (const float*)d_in[1];
    float* out = (float*)d_out;

    char* ws = (char*)d_ws;
    size_t off = 0;
    auto alloc = [&](size_t bytes) -> void* {
        void* p = ws + off;
        off += (bytes + 255) & ~(size_t)255;
        return p;
    };
    uint32_t* hist  = (uint32_t*)alloc(4096 * 4);   // hist+meta contiguous: one memset
    uint32_t* meta  = (uint32_t*)alloc(64);
    uint32_t* keys  = (uint32_t*)alloc((size_t)N_TOT * 4);
    uint64_t* cand  = (uint64_t*)alloc((size_t)CAP * 8);
    float4*   P     = (float4*)alloc((size_t)K_PRE * 16);
    uint64_t* yk    = (uint64_t*)alloc((size_t)K_PRE * 8);
    float4*   OP    = (float4*)alloc((size_t)K_PRE * 16);
    float4*   Q     = (float4*)alloc((size_t)K_PRE * 16);
    float*    Bnd   = (float*)alloc((size_t)K_PRE * 4);
    uint32_t* mask  = (uint32_t*)alloc((size_t)ROWS_PAD * MW * 4);   // ~4.5 MB

    hipMemsetAsync(hist, 0, 4096 * 4 + 256, stream);   // hist + meta
    k_keys_hist<<<N_TOT / 256, 256, 0, stream>>>(scores, deltas, keys, hist);
    k_findbin_compact<<<N_TOT / 256, 256, 0, stream>>>(hist, keys, cand, meta + 1);
    k_rank_props<<<1024, 256, 0, stream>>>(cand, meta, deltas, P, yk);
    k_rank_y2<<<375, 256, 0, stream>>>(yk, P, OP, Q, Bnd);
    k_mask<<<dim3(ROWB, COLB), 256, 0, stream>>>(Q, Bnd, mask);
    k_scan<<<1, 256, 0, stream>>>(mask, OP, out);
}

// Round 9
// 239.137 us; speedup vs baseline: 2.4606x; 1.0757x over previous
//
#include <hip/hip_runtime.h>
#include <cstdint>
#include <cstddef>

#define N_TOT   147456      // 9*128*128
#define K_PRE   6000
#define K_POST  300
#define CAP     32768       // candidate cap (expected ~9.2K)
#define MW      188         // 6016 bits per mask row -> 188 u32 words
#define ROWS_PAD 6016
#define NCHUNK  94
#define CT      128         // k_mask columns per tile
#define ROWB    24
#define COLB    47          // ceil(6000/128)

__constant__ float c_sizes[9] = {4.f,8.f,12.f,16.f,24.f,32.f,48.f,64.f,96.f};

// Bit-exact replication of reference box math (anchor + delta, clip).
__device__ __forceinline__ void compute_box(int idx, const float* __restrict__ deltas,
                                            float& px1, float& py1, float& pw, float& ph) {
    int a   = idx >> 14;
    int rem = idx & 16383;
    int h   = rem >> 7;
    int w   = rem & 127;
    float s    = c_sizes[a];
    float half = s * 0.5f;
    const float4 d = *(const float4*)(deltas + (size_t)a * 65536 + (size_t)rem * 4);
    float b0 = (((float)h + 0.5f) - half) + d.x;
    float b1 = (((float)w + 0.5f) - half) + d.y;
    float b2 = s + d.z;
    float b3 = s + d.w;
    b0 = fmaxf(b0, 0.0f); b1 = fmaxf(b1, 0.0f);
    b2 = fmaxf(b2, 0.0f); b3 = fmaxf(b3, 0.0f);
    float x1 = b0, y1 = b1;
    float x2 = b0 + b2, y2 = b1 + b3;
    x1 = fminf(x1, 128.0f); y1 = fminf(y1, 128.0f);
    x2 = fminf(x2, 128.0f); y2 = fminf(y2, 128.0f);
    px1 = x1; py1 = y1; pw = x2 - x1; ph = y2 - y1;
}

__device__ __forceinline__ uint32_t waveReduceSum(uint32_t v) {
    #pragma unroll
    for (int o = 32; o > 0; o >>= 1) v += __shfl_xor(v, o, 64);
    return v;
}

__global__ void k_keys_hist(const float* __restrict__ scores, const float* __restrict__ deltas,
                            uint32_t* __restrict__ keys, uint32_t* __restrict__ hist) {
    __shared__ uint32_t lh[4096];
    for (int i = threadIdx.x; i < 4096; i += 256) lh[i] = 0u;
    __syncthreads();
    int idx = blockIdx.x * 256 + threadIdx.x;
    float px1, py1, pw, ph;
    compute_box(idx, deltas, px1, py1, pw, ph);
    bool keep = (pw >= 3.0f) && (ph >= 3.0f);
    float sc = scores[idx];
    uint32_t key = keep ? __float_as_uint(sc) : 0u;
    keys[idx] = key;
    atomicAdd(&lh[key >> 20], 1u);
    __syncthreads();
    for (int i = threadIdx.x; i < 4096; i += 256) {
        uint32_t v = lh[i];
        if (v) atomicAdd(&hist[i], v);
    }
}

// per-block findbin (parallel suffix-scan, no serial walk) + compact slice
__global__ void k_findbin_compact(const uint32_t* __restrict__ hist,
                                  const uint32_t* __restrict__ keys,
                                  uint64_t* __restrict__ cand, uint32_t* counter) {
    __shared__ uint32_t lh[4096];
    __shared__ uint32_t seg[256];
    __shared__ uint32_t bsh;
    for (int i = threadIdx.x; i < 4096; i += 256) lh[i] = hist[i];
    __syncthreads();
    uint32_t s = 0;
    #pragma unroll
    for (int q = 0; q < 16; q++) s += lh[threadIdx.x * 16 + q];
    seg[threadIdx.x] = s;
    __syncthreads();
    // suffix-sum scan (Hillis-Steele, 8 steps): seg[t] = sum of segments >= t
    for (int off = 1; off < 256; off <<= 1) {
        uint32_t v = seg[threadIdx.x];
        if (threadIdx.x + off < 256) v += seg[threadIdx.x + off];
        __syncthreads();
        seg[threadIdx.x] = v;
        __syncthreads();
    }
    uint32_t St  = seg[threadIdx.x];
    uint32_t St1 = (threadIdx.x < 255) ? seg[threadIdx.x + 1] : 0u;
    if (St >= K_PRE && St1 < K_PRE) {     // exactly one thread (when total >= K_PRE)
        uint32_t c2 = St1;
        uint32_t bstar = 0u;
        for (int q = 15; q >= 0; q--) {
            c2 += lh[threadIdx.x * 16 + q];
            if (c2 >= K_PRE) { bstar = (uint32_t)(threadIdx.x * 16 + q); break; }
        }
        bsh = bstar;
    }
    if (threadIdx.x == 0 && seg[0] < K_PRE) bsh = 0u;   // degenerate guard
    __syncthreads();
    uint32_t bstar = bsh;
    int idx = blockIdx.x * 256 + threadIdx.x;
    uint32_t key = keys[idx];
    if ((key >> 20) >= bstar) {
        uint32_t pos = atomicAdd(counter, 1u);
        if (pos < CAP) cand[pos] = ((uint64_t)key << 32) | (uint32_t)(~(uint32_t)idx);
    }
}

// rank-by-count (exact top_k order: score desc, idx asc) fused with props/ykey
// generation: rank r in [0,6000) gets P[r] (box) and yk[r] (y2-desc stable key).
__global__ void k_rank_props(const uint64_t* __restrict__ cand, const uint32_t* __restrict__ meta,
                             const float* __restrict__ deltas,
                             float4* __restrict__ P, uint64_t* __restrict__ yk) {
    uint32_t C = meta[1];
    if (C > CAP) C = CAP;
    int lane = threadIdx.x & 63;
    uint32_t wid = (uint32_t)(blockIdx.x * 4 + (threadIdx.x >> 6));
    uint32_t stride = gridDim.x * 4;
    uint32_t nGroups = (C + 3) >> 2;
    for (uint32_t g = wid; g < nGroups; g += stride) {
        uint32_t b = g * 4;
        uint64_t m0 = (b + 0 < C) ? cand[b + 0] : ~0ull;
        uint64_t m1 = (b + 1 < C) ? cand[b + 1] : ~0ull;
        uint64_t m2 = (b + 2 < C) ? cand[b + 2] : ~0ull;
        uint64_t m3 = (b + 3 < C) ? cand[b + 3] : ~0ull;
        uint32_t c0 = 0, c1 = 0, c2 = 0, c3 = 0;
        for (uint32_t j = lane; j < C; j += 64) {
            uint64_t k = cand[j];
            c0 += (k > m0) ? 1u : 0u;
            c1 += (k > m1) ? 1u : 0u;
            c2 += (k > m2) ? 1u : 0u;
            c3 += (k > m3) ? 1u : 0u;
        }
        c0 = waveReduceSum(c0); c1 = waveReduceSum(c1);
        c2 = waveReduceSum(c2); c3 = waveReduceSum(c3);
        if (lane == 0) {
            uint64_t mm[4] = {m0, m1, m2, m3};
            uint32_t cc[4] = {c0, c1, c2, c3};
            #pragma unroll
            for (int q = 0; q < 4; q++) {
                if (b + q < C && cc[q] < K_PRE) {
                    uint32_t r = cc[q];
                    int idx = (int)(~((uint32_t)mm[q]));
                    float px1, py1, pw, ph;
                    compute_box(idx, deltas, px1, py1, pw, ph);
                    P[r] = make_float4(px1, py1, pw, ph);
                    float y2 = py1 + ph;
                    yk[r] = ((uint64_t)__float_as_uint(y2) << 32) | (uint32_t)(~r);
                }
            }
        }
    }
}

// stable y2-desc rank; writes y2-ordered props OP, corners Q, and the exact
// div-free boundary: pred( round(d/area) >= 0.7f ) <=> d >= Bnd.
// M = 0.7f - 2^-25; M*(double)area exact; Bnd = smallest fp32 > M*area.
__global__ void k_rank_y2(const uint64_t* __restrict__ ykey, const float4* __restrict__ P,
                          float4* __restrict__ OP, float4* __restrict__ Q, float* __restrict__ Bnd) {
    int lane = threadIdx.x & 63;
    int wid  = (blockIdx.x * 256 + threadIdx.x) >> 6;   // 0..1499
    uint32_t b = wid * 4;
    uint64_t m0 = ykey[b + 0], m1 = ykey[b + 1], m2 = ykey[b + 2], m3 = ykey[b + 3];
    uint32_t c0 = 0, c1 = 0, c2 = 0, c3 = 0;
    for (uint32_t j = lane; j < K_PRE; j += 64) {
        uint64_t k = ykey[j];
        c0 += (k > m0) ? 1u : 0u;
        c1 += (k > m1) ? 1u : 0u;
        c2 += (k > m2) ? 1u : 0u;
        c3 += (k > m3) ? 1u : 0u;
    }
    c0 = waveReduceSum(c0); c1 = waveReduceSum(c1);
    c2 = waveReduceSum(c2); c3 = waveReduceSum(c3);
    if (lane == 0) {
        const double Mc = (double)0.7f - 0x1.0p-25;
        uint32_t rnk[4] = {c0, c1, c2, c3};
        #pragma unroll
        for (int q = 0; q < 4; q++) {
            float4 p = P[b + q];
            uint32_t cnt = rnk[q];
            OP[cnt] = p;
            float x1 = p.x, y1 = p.y;
            float x2 = x1 + p.z, y2 = y1 + p.w;
            float area = fmaxf((x2 - x1) * (y2 - y1), 1e-6f);
            Q[cnt] = make_float4(x1, y1, x2, y2);
            double c = Mc * (double)area;       // exact
            float Bf = (float)c;
            if (!((double)Bf > c)) Bf = __int_as_float(__float_as_int(Bf) + 1);
            Bnd[cnt] = Bf;
        }
    }
}

// suppression bitmask, tiled: lanes = rows, columns LDS-broadcast; div-free.
// CT=128 -> 1128 blocks (~4.4/CU) for latency hiding.
__global__ void __launch_bounds__(256) k_mask(const float4* __restrict__ Q,
                                              const float* __restrict__ Bnd,
                                              uint32_t* __restrict__ mask) {
    __shared__ float4 qs[CT];
    __shared__ float  bs[CT];
    int i  = blockIdx.x * 256 + threadIdx.x;     // row
    int c0 = blockIdx.y * CT;                    // first column of tile
    int ncols = min(CT, K_PRE - c0);
    bool rowok = (i < K_PRE);
    float4 qi = rowok ? Q[i] : make_float4(0.f, 0.f, 0.f, 0.f);
    for (int j = threadIdx.x; j < ncols; j += 256) {
        qs[j] = Q[c0 + j];
        bs[j] = Bnd[c0 + j];
    }
    __syncthreads();
    int nw = (ncols + 31) >> 5;
    for (int w = 0; w < nw; w++) {
        uint32_t bits = 0u;
        int jb = w * 32;
        int jn = min(32, ncols - jb);
        #pragma unroll 8
        for (int b = 0; b < jn; b++) {
            int j = jb + b;
            float4 qj = qs[j];
            float iw = fminf(qi.z, qj.z) - fmaxf(qi.x, qj.x) + 1.0f;
            iw = fmaxf(iw, 0.0f);
            float ih = fminf(qi.w, qj.w) - fmaxf(qi.y, qj.y) + 1.0f;
            ih = fmaxf(ih, 0.0f);
            float d = iw * ih;
            bits |= (d >= bs[j]) ? (1u << b) : 0u;
        }
        if (rowok) {
            int gj = c0 + jb;
            uint32_t selfo = (uint32_t)(i - gj);
            if (selfo < 32u) bits &= ~(1u << selfo);     // j == i excluded
            mask[(size_t)i * MW + (gj >> 5)] = bits;
        }
    }
}

// Serial active scan + final validity + emit, single block.
// Decide: active(i) = no earlier active k with mask[k][i]; leader iteration
// over uniform work mask, #iters == #survivors. OR phase: active rows of this
// chunk ORed into ALL 188 rem words -> at end rem = union over active rows of
// their mask rows; final valid = activeBits & ~rem (covers backward kills).
__global__ void __launch_bounds__(256) k_scan(const uint32_t* __restrict__ mask,
                                              const float4* __restrict__ OP,
                                              float* __restrict__ out) {
    __shared__ uint32_t rem[MW];
    __shared__ uint32_t sidx[64];
    __shared__ uint32_t svL[MW];
    __shared__ uint32_t nsSh;
    __shared__ uint32_t pref[MW];
    int tid = threadIdx.x;
    for (int i = tid; i < MW; i += 256) rem[i] = 0u;
    for (int i = tid; i < K_POST * 4; i += 256) out[i] = 0.0f;
    __syncthreads();
    uint2 mr = make_uint2(0u, 0u);
    if (tid < 64) mr = *(const uint2*)(mask + (size_t)tid * MW);   // chunk 0 rows
    for (int c = 0; c < NCHUNK; c++) {
        int base = c * 64;
        int rows = min(64, K_PRE - base);
        if (tid < 64) {
            uint64_t v = ~(((uint64_t)rem[2 * c + 1] << 32) | (uint64_t)rem[2 * c]);
            if (rows < 64) v &= ((1ull << rows) - 1ull);
            uint64_t work = v, surv = 0ull;
            while (work) {                      // leader iteration
                int k = __ffsll((unsigned long long)work) - 1;
                surv |= 1ull << k;
                uint64_t rowk =
                    ((uint64_t)(uint32_t)__builtin_amdgcn_readlane((int)mr.y, k) << 32)
                  |  (uint64_t)(uint32_t)__builtin_amdgcn_readlane((int)mr.x, k);
                work &= ~rowk;
                work &= ~(1ull << k);
            }
            uint32_t ns = (uint32_t)__popcll(surv);
            if (tid == 0) {
                svL[2 * c]     = (uint32_t)surv;
                svL[2 * c + 1] = (uint32_t)(surv >> 32);
                nsSh = ns;
            }
            if ((surv >> tid) & 1ull) {
                uint32_t pr = __popcll(surv & ((1ull << tid) - 1ull));
                sidx[pr] = (uint32_t)(base + tid);
            }
            if (surv) {             // pad sidx to x16 with first survivor (OR-idempotent)
                uint32_t nsPad = (ns + 15u) & ~15u;
                uint32_t first = (uint32_t)base +
                                 (uint32_t)(__ffsll((unsigned long long)surv) - 1);
                if ((uint32_t)tid >= ns && (uint32_t)tid < nsPad) sidx[tid] = first;
            }
            if (c + 1 < NCHUNK)     // prefetch next chunk rows (overlaps OR phase)
                mr = *(const uint2*)(mask + (size_t)(base + 64 + tid) * MW + 2 * (c + 1));
        }
        __syncthreads();
        int w = tid - 64;
        if (w >= 0 && w < MW) {
            uint32_t nsPad = (nsSh + 15u) & ~15u;
            uint32_t acc = rem[w];
            for (uint32_t t2 = 0; t2 < nsPad; t2 += 16) {
                uint32_t r[16];
                #pragma unroll
                for (int q = 0; q < 16; q++)
                    r[q] = mask[(size_t)sidx[t2 + q] * MW + w];
                uint32_t o = 0u;
                #pragma unroll
                for (int q = 0; q < 16; q++) o |= r[q];
                acc |= o;
            }
            rem[w] = acc;
        }
        __syncthreads();
    }
    // final validity + emit first 300 (tail already zeroed above)
    if (tid < MW) {
        uint32_t vv = svL[tid] & ~rem[tid];
        if (tid == MW - 1) vv &= 0xFFFFu;
        rem[tid] = vv;
    }
    __syncthreads();
    if (tid == 0) {
        uint32_t run = 0;
        for (int w2 = 0; w2 < MW; w2++) { pref[w2] = run; run += (uint32_t)__popc(rem[w2]); }
    }
    __syncthreads();
    if (tid < MW) {
        uint32_t b = rem[tid];
        uint32_t r = pref[tid];
        int basebit = tid * 32;
        while (b && r < K_POST) {
            int bit = __ffs(b) - 1;
            b &= b - 1u;
            float4 pp = OP[basebit + bit];
            *(float4*)(out + (size_t)r * 4) = pp;
            r++;
        }
    }
}

extern "C" void kernel_launch(void* const* d_in, const int* in_sizes, int n_in,
                              void* d_out, int out_size, void* d_ws, size_t ws_size,
                              hipStream_t stream) {
    (void)in_sizes; (void)n_in; (void)out_size; (void)ws_size;
    const float* scores = (const float*)d_in[0];
    const float* deltas = (const float*)d_in[1];
    float* out = (float*)d_out;

    char* ws = (char*)d_ws;
    size_t off = 0;
    auto alloc = [&](size_t bytes) -> void* {
        void* p = ws + off;
        off += (bytes + 255) & ~(size_t)255;
        return p;
    };
    uint32_t* hist  = (uint32_t*)alloc(4096 * 4);   // hist+meta contiguous: one memset
    uint32_t* meta  = (uint32_t*)alloc(64);
    uint32_t* keys  = (uint32_t*)alloc((size_t)N_TOT * 4);
    uint64_t* cand  = (uint64_t*)alloc((size_t)CAP * 8);
    float4*   P     = (float4*)alloc((size_t)K_PRE * 16);
    uint64_t* yk    = (uint64_t*)alloc((size_t)K_PRE * 8);
    float4*   OP    = (float4*)alloc((size_t)K_PRE * 16);
    float4*   Q     = (float4*)alloc((size_t)K_PRE * 16);
    float*    Bnd   = (float*)alloc((size_t)K_PRE * 4);
    uint32_t* mask  = (uint32_t*)alloc((size_t)ROWS_PAD * MW * 4);   // ~4.5 MB

    hipMemsetAsync(hist, 0, 4096 * 4 + 256, stream);   // hist + meta
    k_keys_hist<<<N_TOT / 256, 256, 0, stream>>>(scores, deltas, keys, hist);
    k_findbin_compact<<<N_TOT / 256, 256, 0, stream>>>(hist, keys, cand, meta + 1);
    k_rank_props<<<1024, 256, 0, stream>>>(cand, meta, deltas, P, yk);
    k_rank_y2<<<375, 256, 0, stream>>>(yk, P, OP, Q, Bnd);
    k_mask<<<dim3(ROWB, COLB), 256, 0, stream>>>(Q, Bnd, mask);
    k_scan<<<1, 256, 0, stream>>>(mask, OP, out);
}